// Round 1
// baseline (199.988 us; speedup 1.0000x reference)
//
#include <hip/hip_runtime.h>
#include <hip/hip_bf16.h>

// Skipgram negative-sampling loss on MI355X.
// N=65536 samples, D=128 dims, K=10 negatives. fp32 tables.
// Strategy: half-wave (32 lanes) per sample; each lane holds a float4 (32*4=128
// dims). 11 dots per sample via per-lane FMA + 5-step __shfl_xor butterfly
// (masks 16..1 stay inside each 32-lane half of the wave64). Scalar output =
// mean, accumulated via per-block partial + one fp32 atomicAdd per block.

#define N_SAMPLES 65536
#define N_DIMS 128
#define K_NEG 10

__global__ void zero_out_kernel(float* out) {
    if (threadIdx.x == 0 && blockIdx.x == 0) out[0] = 0.0f;
}

__device__ __forceinline__ float log_sigmoid(float x) {
    // log(sigmoid(x)) = min(x,0) - log1p(exp(-|x|)); stable for all x.
    float ax = fabsf(x);
    return fminf(x, 0.0f) - log1pf(__expf(-ax));
}

__device__ __forceinline__ float half_wave_reduce(float v) {
    // Butterfly across the 32 lanes of this half-wave (xor masks < 32 never
    // cross the 32-lane boundary of a wave64).
    v += __shfl_xor(v, 16);
    v += __shfl_xor(v, 8);
    v += __shfl_xor(v, 4);
    v += __shfl_xor(v, 2);
    v += __shfl_xor(v, 1);
    return v;
}

__global__ __launch_bounds__(256) void skipgram_kernel(
        const int* __restrict__ input_idx,
        const int* __restrict__ output_idx,
        const int* __restrict__ neg_idx,
        const float* __restrict__ W_in,
        const float* __restrict__ W_out,
        float* __restrict__ out)
{
    const int lane   = threadIdx.x & 31;   // lane within half-wave
    const int half   = threadIdx.x >> 5;   // half-wave id within block (0..7)
    const int halves_per_block = blockDim.x >> 5;
    const int halves_total = gridDim.x * halves_per_block;
    const int h0 = blockIdx.x * halves_per_block + half;

    float local = 0.0f;

    for (int n = h0; n < N_SAMPLES; n += halves_total) {
        const int ii = input_idx[n];
        const float4 a = ((const float4*)(W_in + (size_t)ii * N_DIMS))[lane];

        // Positive sample
        const int oi = output_idx[n];
        const float4 b = ((const float4*)(W_out + (size_t)oi * N_DIMS))[lane];
        float p = a.x * b.x + a.y * b.y + a.z * b.z + a.w * b.w;
        p = half_wave_reduce(p);
        float acc = log_sigmoid(p);

        // Negative samples
        #pragma unroll
        for (int k = 0; k < K_NEG; ++k) {
            const int ni = neg_idx[n * K_NEG + k];
            const float4 c = ((const float4*)(W_out + (size_t)ni * N_DIMS))[lane];
            float q = a.x * c.x + a.y * c.y + a.z * c.z + a.w * c.w;
            q = half_wave_reduce(q);
            acc += log_sigmoid(-q);  // noise = -dot
        }
        local += acc;
    }

    // local is identical across all 32 lanes of the half (butterfly leaves the
    // full sum in every lane). Block-level reduce via LDS, one atomic per block.
    __shared__ float sdata[8];
    if (lane == 0) sdata[half] = local;
    __syncthreads();
    if (threadIdx.x == 0) {
        float s = 0.0f;
        #pragma unroll
        for (int i = 0; i < 8; ++i) s += sdata[i];
        atomicAdd(out, s * (1.0f / (float)N_SAMPLES));
    }
}

extern "C" void kernel_launch(void* const* d_in, const int* in_sizes, int n_in,
                              void* d_out, int out_size, void* d_ws, size_t ws_size,
                              hipStream_t stream) {
    const int*   input_idx  = (const int*)d_in[0];
    const int*   output_idx = (const int*)d_in[1];
    const int*   neg_idx    = (const int*)d_in[2];
    const float* W_in       = (const float*)d_in[3];
    const float* W_out      = (const float*)d_in[4];
    float* out = (float*)d_out;

    // Harness re-poisons d_out with 0xAA before every timed replay: zero it.
    zero_out_kernel<<<1, 64, 0, stream>>>(out);

    const int block = 256;
    const int grid  = 2048;  // 2048 blocks * 8 halves = 16384 halves; 4 samples each
    skipgram_kernel<<<grid, block, 0, stream>>>(
        input_idx, output_idx, neg_idx, W_in, W_out, out);
}

// Round 2
// 164.342 us; speedup vs baseline: 1.2169x; 1.2169x over previous
//
#include <hip/hip_runtime.h>
#include <hip/hip_bf16.h>

// Skipgram negative-sampling loss on MI355X — round 2.
// R1 showed VALU-overhead-bound (VALUBusy 64%, HBM 23%): 5-step butterfly and
// libm log1pf amortized over only 2 samples/wave dominated. Now: 8 lanes per
// sample (16 dims/lane), 3-step butterfly, hardware __logf/__expf log-sigmoid.
// A wave covers 8 samples -> reduction+transcendental cost drops ~6x.

#define N_SAMPLES 65536
#define N_DIMS 128
#define K_NEG 10

__global__ void zero_out_kernel(float* out) {
    if (threadIdx.x == 0 && blockIdx.x == 0) out[0] = 0.0f;
}

__device__ __forceinline__ float log_sigmoid_fast(float x) {
    // log(sigmoid(x)) = min(x,0) - log(1 + exp(-|x|)); hardware exp/log.
    float ax = fabsf(x);
    return fminf(x, 0.0f) - __logf(1.0f + __expf(-ax));
}

__device__ __forceinline__ float dot4(float4 a, float4 b) {
    return a.x * b.x + a.y * b.y + a.z * b.z + a.w * b.w;
}

__device__ __forceinline__ float group8_reduce(float v) {
    // Sum across the 8 lanes of this group (xor masks 4,2,1 never cross an
    // 8-lane boundary).
    v += __shfl_xor(v, 4);
    v += __shfl_xor(v, 2);
    v += __shfl_xor(v, 1);
    return v;
}

__global__ __launch_bounds__(256) void skipgram_kernel(
        const int* __restrict__ input_idx,
        const int* __restrict__ output_idx,
        const int* __restrict__ neg_idx,
        const float* __restrict__ W_in,
        const float* __restrict__ W_out,
        float* __restrict__ out)
{
    const int g = threadIdx.x & 7;                       // lane within group
    const int n = (blockIdx.x * blockDim.x + threadIdx.x) >> 3;  // sample id
    // grid sized exactly: 2048 blocks * 32 groups = 65536 samples

    // Load this sample's input vector: lane g holds dims {4*(j*8+g)..+3}, j=0..3
    const int ii = input_idx[n];
    const float4* __restrict__ arow = (const float4*)(W_in + (size_t)ii * N_DIMS);
    const float4 a0 = arow[0 * 8 + g];
    const float4 a1 = arow[1 * 8 + g];
    const float4 a2 = arow[2 * 8 + g];
    const float4 a3 = arow[3 * 8 + g];

    float acc;
    {
        const int oi = output_idx[n];
        const float4* __restrict__ br = (const float4*)(W_out + (size_t)oi * N_DIMS);
        float p = dot4(a0, br[0 * 8 + g]) + dot4(a1, br[1 * 8 + g])
                + dot4(a2, br[2 * 8 + g]) + dot4(a3, br[3 * 8 + g]);
        p = group8_reduce(p);
        acc = log_sigmoid_fast(p);
    }

    #pragma unroll
    for (int k = 0; k < K_NEG; ++k) {
        const int ni = neg_idx[n * K_NEG + k];
        const float4* __restrict__ cr = (const float4*)(W_out + (size_t)ni * N_DIMS);
        float q = dot4(a0, cr[0 * 8 + g]) + dot4(a1, cr[1 * 8 + g])
                + dot4(a2, cr[2 * 8 + g]) + dot4(a3, cr[3 * 8 + g]);
        q = group8_reduce(q);
        acc += log_sigmoid_fast(-q);   // noise = -dot
    }

    // acc is identical across the 8 lanes of the group. One value per group ->
    // LDS (32 groups/block) -> single 32-lane butterfly -> one atomic per block.
    __shared__ float sdata[32];
    if (g == 0) sdata[threadIdx.x >> 3] = acc;
    __syncthreads();
    if (threadIdx.x < 32) {
        float s = sdata[threadIdx.x];
        s += __shfl_xor(s, 16);
        s += __shfl_xor(s, 8);
        s += __shfl_xor(s, 4);
        s += __shfl_xor(s, 2);
        s += __shfl_xor(s, 1);
        if (threadIdx.x == 0)
            atomicAdd(out, s * (1.0f / (float)N_SAMPLES));
    }
}

extern "C" void kernel_launch(void* const* d_in, const int* in_sizes, int n_in,
                              void* d_out, int out_size, void* d_ws, size_t ws_size,
                              hipStream_t stream) {
    const int*   input_idx  = (const int*)d_in[0];
    const int*   output_idx = (const int*)d_in[1];
    const int*   neg_idx    = (const int*)d_in[2];
    const float* W_in       = (const float*)d_in[3];
    const float* W_out      = (const float*)d_in[4];
    float* out = (float*)d_out;

    // Harness re-poisons d_out with 0xAA before every timed replay: zero it.
    zero_out_kernel<<<1, 64, 0, stream>>>(out);

    const int block = 256;                       // 32 groups of 8 lanes
    const int grid  = N_SAMPLES / (block / 8);   // 2048 blocks, exact cover
    skipgram_kernel<<<grid, block, 0, stream>>>(
        input_idx, output_idx, neg_idx, W_in, W_out, out);
}